// Round 9
// baseline (96.281 us; speedup 1.0000x reference)
//
#include <hip/hip_runtime.h>
#include <hip/hip_bf16.h>
#include <string.h>

#define N 4096
#define D 512
#define NB 32            // N/128 regions; triangle regions = NB*(NB+1)/2 = 528
#define NBLK (NB*(NB+1)/2)
#define MARGIN 0.5f
#define FINF __builtin_huge_valf()
#define UINF 0x7F800000u

typedef __attribute__((ext_vector_type(4))) float f32x4;
typedef long fp8x8;      // 8 packed fp8-e4m3 (i64 MFMA operand)

__device__ inline float wave_sum(float v){
  #pragma unroll
  for (int off=32; off>0; off>>=1) v += __shfl_down(v, off, 64);
  return v;
}

// Pass 0: X (f32) -> fp8 e4m3, row norms, accumulator init. 512 x 256.
__global__ __launch_bounds__(256) void prep_kernel(const float* __restrict__ X,
    unsigned char* __restrict__ Xq, float* __restrict__ sq,
    unsigned int* __restrict__ hp2u, unsigned int* __restrict__ nm2u,
    float* __restrict__ out){
  const int tid = threadIdx.x;
  const int wave = tid >> 6, lane = tid & 63;
  const int l128 = tid & 127;        // 128 threads per row
  const int rsel = tid >> 7;         // which of the 2 rows this pass
  __shared__ float red[4];
  #pragma unroll
  for (int rr = 0; rr < 4; ++rr){    // 8 rows per block
    const int row = blockIdx.x*8 + rr*2 + rsel;
    const float4 v = *(const float4*)(X + (size_t)row*D + l128*4);
    int p0 = __builtin_amdgcn_cvt_pk_fp8_f32(v.x, v.y, 0, false);
    int p1 = __builtin_amdgcn_cvt_pk_fp8_f32(v.z, v.w, 0, false);
    unsigned int packed = (p0 & 0xFFFFu) | ((unsigned int)(p1 & 0xFFFFu) << 16);
    *(unsigned int*)(Xq + (size_t)row*D + l128*4) = packed;
    float ss = v.x*v.x + v.y*v.y + v.z*v.z + v.w*v.w;
    ss = wave_sum(ss);
    if (lane == 0) red[wave] = ss;
    __syncthreads();
    if (tid == 0)   sq[row] = red[0] + red[1];   // rsel==0 row
    if (tid == 128) sq[row] = red[2] + red[3];   // rsel==1 row
    __syncthreads();
  }
  if (tid < 8){
    hp2u[blockIdx.x*8 + tid] = 0u;   // max-accumulator (d^2 domain, >= 0)
    nm2u[blockIdx.x*8 + tid] = UINF; // +inf: min-accumulator
  }
  if (blockIdx.x == 0 && tid == 0) out[0] = 0.0f;
}

// Staging: rows are 64 B = 4 x 16B slots. LDS slot s of row r holds global
// chunk c = s ^ (r&3). Lane l: row = l>>2, slot = l&3 (dest = base+l*16),
// fetches global chunk g = (l&3) ^ ((l>>2)&3). 128 rows: 2 issues/wave.
#define STAGE(Abuf, Bbuf, it) do { \
  const int k0_ = (it)*64; \
  _Pragma("unroll") \
  for (int c_=0;c_<2;c_++){ \
    const int rg_ = wave*32 + c_*16; \
    const unsigned char* ga_ = Xq + (size_t)(row0 + rg_ + srow)*D + k0_ + g16*16; \
    const unsigned char* gb_ = Xq + (size_t)(col0 + rg_ + srow)*D + k0_ + g16*16; \
    __builtin_amdgcn_global_load_lds((const __attribute__((address_space(1))) void*)ga_, \
        (__attribute__((address_space(3))) void*)((Abuf) + rg_*64), 16, 0, 0); \
    __builtin_amdgcn_global_load_lds((const __attribute__((address_space(1))) void*)gb_, \
        (__attribute__((address_space(3))) void*)((Bbuf) + rg_*64), 16, 0, 0); \
  } \
} while(0)

// Fragment reads with wave-quadrant rows: A rows wr+a*16+fr, B rows
// wc+b*16+fr; chunk c_=h*2+(q>>1), half (q&1)*8.
#define COMPUTE(Abuf, Bbuf) do { \
  fp8x8 af_[2][4], bf_[2][4]; \
  _Pragma("unroll") \
  for (int h_=0;h_<2;h_++){ \
    const int c_ = h_*2 + (q>>1); \
    const int hb_ = (q&1)*8; \
    _Pragma("unroll") \
    for (int a_=0;a_<4;a_++){ \
      const int ra_ = wr + a_*16 + fr; \
      af_[h_][a_] = *(const fp8x8*)((Abuf) + ra_*64 + (((c_) ^ (ra_&3))*16) + hb_); \
      const int rb_ = wc + a_*16 + fr; \
      bf_[h_][a_] = *(const fp8x8*)((Bbuf) + rb_*64 + (((c_) ^ (rb_&3))*16) + hb_); \
    } \
  } \
  _Pragma("unroll") \
  for (int h_=0;h_<2;h_++) \
    _Pragma("unroll") \
    for (int a_=0;a_<4;a_++) \
      _Pragma("unroll") \
      for (int b_=0;b_<4;b_++) \
        acc[a_][b_] = __builtin_amdgcn_mfma_f32_16x16x32_fp8_fp8(af_[h_][a_], bf_[h_][b_], acc[a_][b_], 0, 0, 0); \
} while(0)

// R23: FULL-K one-shot staging. All 8 K-tiles (128 KB) issue before a
// SINGLE vmcnt(0)+barrier — the 8 per-step latency exposures of every
// prior variant collapse into one fully-overlapped load burst. After the
// barrier: straight-line LDS reads + 256 MFMA/wave, zero further syncs.
// 132 KB LDS -> 1 block/CU; 528 blocks = ~2.06 rounds + tail.
__global__ __launch_bounds__(256,2) void gemm_fused(const unsigned char* __restrict__ Xq,
    const float* __restrict__ sq, const int* __restrict__ lab,
    unsigned int* __restrict__ hp2u, unsigned int* __restrict__ nm2u){
  __shared__ __align__(16) unsigned char As[8*128*64];   // 64 KB (8 K-tiles)
  __shared__ __align__(16) unsigned char Bs[8*128*64];   // 64 KB
  __shared__ float sqi[128];
  __shared__ float sqj[128];
  __shared__ int labi_s[128];
  __shared__ int labj_s[128];
  __shared__ unsigned int hpl[128], nml[128];   // region-row combine
  __shared__ unsigned int hpc[128], nmc[128];   // region-col combine

  // linear block -> region (bi, bj) with bi <= bj
  int rem = blockIdx.x, bi = 0;
  while (rem >= NB - bi){ rem -= NB - bi; bi++; }
  const int bj = bi + rem;
  const int row0 = bi * 128, col0 = bj * 128;

  const int tid = threadIdx.x;
  const int wave = tid >> 6, lane = tid & 63;
  const int wr = (wave >> 1) * 64, wc = (wave & 1) * 64;   // wave's 64x64 quadrant
  const int fr = lane & 15, q = lane >> 4;

  if (tid < 128) {
    sqi[tid] = sq[row0 + tid]; sqj[tid] = sq[col0 + tid];
    labi_s[tid] = lab[row0 + tid]; labj_s[tid] = lab[col0 + tid];
    hpl[tid] = 0u; nml[tid] = UINF; hpc[tid] = 0u; nmc[tid] = UINF;
  }

  const int srow = lane >> 2;
  const int g16  = (lane & 3) ^ (srow & 3);

  f32x4 acc[4][4];
  #pragma unroll
  for (int a=0;a<4;a++)
    #pragma unroll
    for (int b=0;b<4;b++)
      acc[a][b] = (f32x4){0.f,0.f,0.f,0.f};

  // One-shot stage: 32 global_load_lds per wave, all in flight at once.
  #pragma unroll
  for (int kt = 0; kt < 8; ++kt)
    STAGE(As + kt*8192, Bs + kt*8192, kt);
  __syncthreads();                 // single vmcnt(0) drain + publish

  // Straight-line compute: no barriers, compiler-scheduled lgkmcnt.
  #pragma unroll
  for (int kt = 0; kt < 8; ++kt)
    COMPUTE(As + kt*8192, Bs + kt*8192);

  // Epilogue. C/D layout: col=lane&15, row=(lane>>4)*4+v (shape-determined).
  const int colq = lane & 15, g4 = lane >> 4, rowq = g4 * 4;
  int   labi_r[16]; float sqi_r[16];
  #pragma unroll
  for (int a=0;a<4;a++)
    #pragma unroll
    for (int v=0;v<4;v++){
      const int iloc = wr + a*16 + rowq + v;
      labi_r[a*4+v] = labi_s[iloc];
      sqi_r[a*4+v]  = sqi[iloc];
    }

  float pmax_r[16], nmin_r[16];
  #pragma unroll
  for (int k=0;k<16;k++){ pmax_r[k] = 0.f; nmin_r[k] = FINF; }
  float cpos[4], cmin[4];

  #pragma unroll
  for (int b=0;b<4;b++){
    const int jloc = wc + b*16 + colq;
    const float sj = sqj[jloc];
    const int lj = labj_s[jloc];
    float cp = 0.f, cn = FINF;
    #pragma unroll
    for (int a=0;a<4;a++)
      #pragma unroll
      for (int v=0;v<4;v++){
        const int k = a*4+v;
        const float d2 = fmaf(acc[a][b][v], -2.0f, sqi_r[k] + sj);
        const bool same = (labi_r[k] == lj);         // covers diag (i==j)
        const float sp = same ? d2 : 0.0f;           // positive candidate
        const float sn = same ? FINF : d2;           // negative candidate
        pmax_r[k] = fmaxf(pmax_r[k], sp);
        nmin_r[k] = fminf(nmin_r[k], sn);
        cp = fmaxf(cp, sp);
        cn = fminf(cn, sn);
      }
    cpos[b] = cp; cmin[b] = cn;
  }

  // Row-direction: xor-reduce across the 16 lanes sharing a row -> LDS atomic.
  #pragma unroll
  for (int k=0;k<16;k++){
    float p = pmax_r[k], n = nmin_r[k];
    #pragma unroll
    for (int m=1;m<16;m<<=1){
      p = fmaxf(p, __shfl_xor(p, m, 64));
      n = fminf(n, __shfl_xor(n, m, 64));
    }
    if (colq == 0){
      const int il = wr + (k>>2)*16 + rowq + (k&3);
      atomicMax(&hpl[il], __float_as_uint(p));                 // p >= 0
      atomicMin(&nml[il], __float_as_uint(fmaxf(n, 0.f)));     // clamp: monotone
    }
  }
  // Column-direction (symmetry): xor-reduce across the 4 lane-groups -> LDS atomic.
  #pragma unroll
  for (int b=0;b<4;b++){
    float p = cpos[b], n = cmin[b];
    p = fmaxf(p, __shfl_xor(p, 16, 64)); p = fmaxf(p, __shfl_xor(p, 32, 64));
    n = fminf(n, __shfl_xor(n, 16, 64)); n = fminf(n, __shfl_xor(n, 32, 64));
    if (g4 == 0){
      const int jl = wc + b*16 + colq;
      atomicMax(&hpc[jl], __float_as_uint(p));
      atomicMin(&nmc[jl], __float_as_uint(fmaxf(n, 0.f)));
    }
  }

  __syncthreads();
  // One global flush: threads 0-127 do region rows, 128-255 region cols.
  if (tid < 128){
    atomicMax(hp2u + row0 + tid, hpl[tid]);
    atomicMin(nm2u + row0 + tid, nml[tid]);
  } else {
    const int t2 = tid - 128;
    atomicMax(hp2u + col0 + t2, hpc[t2]);
    atomicMin(nm2u + col0 + t2, nmc[t2]);
  }
}

// Final: loss = mean(sqrt(hp2)) + mean(max(margin - sqrt(nm2), 0)).
// 16 blocks + one atomicAdd per block; out zeroed by prep.
__global__ __launch_bounds__(256) void final_reduce(const unsigned int* __restrict__ hp2u,
    const unsigned int* __restrict__ nm2u, float* __restrict__ out){
  const int i = blockIdx.x * 256 + threadIdx.x;
  const float hp2 = __uint_as_float(hp2u[i]);
  const float nm2 = __uint_as_float(nm2u[i]);
  float s = sqrtf(hp2 + 1e-12f) + fmaxf(MARGIN - sqrtf(nm2 + 1e-12f), 0.f);
  s = wave_sum(s);
  __shared__ float r[4];
  if ((threadIdx.x & 63) == 0) r[threadIdx.x >> 6] = s;
  __syncthreads();
  if (threadIdx.x == 0)
    atomicAdd(out, (r[0] + r[1] + r[2] + r[3]) * (1.0f / (float)N));
}

extern "C" void kernel_launch(void* const* d_in, const int* in_sizes, int n_in,
                              void* d_out, int out_size, void* d_ws, size_t ws_size,
                              hipStream_t stream) {
  (void)in_sizes; (void)n_in; (void)out_size; (void)ws_size;
  const float* X  = (const float*)d_in[0];
  const int* lab  = (const int*)d_in[1];
  float* out      = (float*)d_out;

  char* ws = (char*)d_ws;
  unsigned char* Xq     = (unsigned char*)ws;                  // 2 MB fp8
  float* sq             = (float*)(Xq + (size_t)N * D);        // 16 KB
  unsigned int* hp2u    = (unsigned int*)(sq + N);             // 16 KB
  unsigned int* nm2u    = hp2u + N;                            // 16 KB

  prep_kernel<<<N/8, 256, 0, stream>>>(X, Xq, sq, hp2u, nm2u, out);
  gemm_fused<<<NBLK, 256, 0, stream>>>(Xq, sq, lab, hp2u, nm2u);
  final_reduce<<<16, 256, 0, stream>>>(hp2u, nm2u, out);
}

// Round 10
// 88.845 us; speedup vs baseline: 1.0837x; 1.0837x over previous
//
#include <hip/hip_runtime.h>
#include <hip/hip_bf16.h>
#include <string.h>

#define N 4096
#define D 512
#define NB 32            // N/128 regions; triangle regions = NB*(NB+1)/2 = 528
#define NBLK (NB*(NB+1)/2)
#define MARGIN 0.5f
#define FINF __builtin_huge_valf()
#define UINF 0x7F800000u

typedef __attribute__((ext_vector_type(4))) float f32x4;
typedef long fp8x8;      // 8 packed fp8-e4m3 (i64 MFMA operand)

__device__ inline float wave_sum(float v){
  #pragma unroll
  for (int off=32; off>0; off>>=1) v += __shfl_down(v, off, 64);
  return v;
}

// Pass 0: X (f32) -> fp8 e4m3, row norms, accumulator init. 512 x 256.
__global__ __launch_bounds__(256) void prep_kernel(const float* __restrict__ X,
    unsigned char* __restrict__ Xq, float* __restrict__ sq,
    unsigned int* __restrict__ hp2u, unsigned int* __restrict__ nm2u,
    float* __restrict__ out){
  const int tid = threadIdx.x;
  const int wave = tid >> 6, lane = tid & 63;
  const int l128 = tid & 127;        // 128 threads per row
  const int rsel = tid >> 7;         // which of the 2 rows this pass
  __shared__ float red[4];
  #pragma unroll
  for (int rr = 0; rr < 4; ++rr){    // 8 rows per block
    const int row = blockIdx.x*8 + rr*2 + rsel;
    const float4 v = *(const float4*)(X + (size_t)row*D + l128*4);
    int p0 = __builtin_amdgcn_cvt_pk_fp8_f32(v.x, v.y, 0, false);
    int p1 = __builtin_amdgcn_cvt_pk_fp8_f32(v.z, v.w, 0, false);
    unsigned int packed = (p0 & 0xFFFFu) | ((unsigned int)(p1 & 0xFFFFu) << 16);
    *(unsigned int*)(Xq + (size_t)row*D + l128*4) = packed;
    float ss = v.x*v.x + v.y*v.y + v.z*v.z + v.w*v.w;
    ss = wave_sum(ss);
    if (lane == 0) red[wave] = ss;
    __syncthreads();
    if (tid == 0)   sq[row] = red[0] + red[1];   // rsel==0 row
    if (tid == 128) sq[row] = red[2] + red[3];   // rsel==1 row
    __syncthreads();
  }
  if (tid < 8){
    hp2u[blockIdx.x*8 + tid] = 0u;   // max-accumulator (d^2 domain, >= 0)
    nm2u[blockIdx.x*8 + tid] = UINF; // +inf: min-accumulator
  }
  if (blockIdx.x == 0 && tid == 0) out[0] = 0.0f;
}

// Staging (8 waves): each wave stages 16 rows of A and 16 of B per tile —
// 2 global_load_lds/wave/tile. LDS slot s of row r holds global chunk
// c = s ^ (r&3); lane l: row = l>>2, slot = l&3, fetches g = (l&3)^((l>>2)&3).
#define STAGE(Abuf, Bbuf, it) do { \
  const int k0_ = (it)*64; \
  const int rg_ = wave*16; \
  const unsigned char* ga_ = Xq + (size_t)(row0 + rg_ + srow)*D + k0_ + g16*16; \
  const unsigned char* gb_ = Xq + (size_t)(col0 + rg_ + srow)*D + k0_ + g16*16; \
  __builtin_amdgcn_global_load_lds((const __attribute__((address_space(1))) void*)ga_, \
      (__attribute__((address_space(3))) void*)((Abuf) + rg_*64), 16, 0, 0); \
  __builtin_amdgcn_global_load_lds((const __attribute__((address_space(1))) void*)gb_, \
      (__attribute__((address_space(3))) void*)((Bbuf) + rg_*64), 16, 0, 0); \
} while(0)

// Fragment reads, wave sub-tile 32x64: A rows wr+a*16+fr (a<2), B rows
// wc+b*16+fr (b<4); chunk c_=h*2+(q>>1), half (q&1)*8. 12 ds_read_b64 +
// 16 MFMA per tile per wave.
#define COMPUTE(Abuf, Bbuf) do { \
  fp8x8 af_[2][2], bf_[2][4]; \
  _Pragma("unroll") \
  for (int h_=0;h_<2;h_++){ \
    const int c_ = h_*2 + (q>>1); \
    const int hb_ = (q&1)*8; \
    _Pragma("unroll") \
    for (int a_=0;a_<2;a_++){ \
      const int ra_ = wr + a_*16 + fr; \
      af_[h_][a_] = *(const fp8x8*)((Abuf) + ra_*64 + (((c_) ^ (ra_&3))*16) + hb_); \
    } \
    _Pragma("unroll") \
    for (int b_=0;b_<4;b_++){ \
      const int rb_ = wc + b_*16 + fr; \
      bf_[h_][b_] = *(const fp8x8*)((Bbuf) + rb_*64 + (((c_) ^ (rb_&3))*16) + hb_); \
    } \
  } \
  _Pragma("unroll") \
  for (int h_=0;h_<2;h_++) \
    _Pragma("unroll") \
    for (int a_=0;a_<2;a_++) \
      _Pragma("unroll") \
      for (int b_=0;b_<4;b_++) \
        acc[a_][b_] = __builtin_amdgcn_mfma_f32_16x16x32_fp8_fp8(af_[h_][a_], bf_[h_][b_], acc[a_][b_], 0, 0, 0); \
} while(0)

// R24: 8 waves/block (512 thr) on the SAME 128x128 tile/528-block grid.
// Grid caps blocks/CU at 2.06, so wave-level TLP is the only remaining
// latency-hiding axis: 16 waves/CU (4/SIMD) vs 8 before, one epilogue per
// block (unlike R5's tile split). Dbuf schedule unchanged from R8.
__global__ __launch_bounds__(512,4) void gemm_fused(const unsigned char* __restrict__ Xq,
    const float* __restrict__ sq, const int* __restrict__ lab,
    unsigned int* __restrict__ hp2u, unsigned int* __restrict__ nm2u){
  __shared__ __align__(16) unsigned char As0[128*64];   // 8 KB
  __shared__ __align__(16) unsigned char Bs0[128*64];   // 8 KB
  __shared__ __align__(16) unsigned char As1[128*64];   // 8 KB
  __shared__ __align__(16) unsigned char Bs1[128*64];   // 8 KB
  __shared__ float sqi[128];
  __shared__ float sqj[128];
  __shared__ int labi_s[128];
  __shared__ int labj_s[128];
  __shared__ unsigned int hpl[128], nml[128];   // region-row combine
  __shared__ unsigned int hpc[128], nmc[128];   // region-col combine

  // linear block -> region (bi, bj) with bi <= bj
  int rem = blockIdx.x, bi = 0;
  while (rem >= NB - bi){ rem -= NB - bi; bi++; }
  const int bj = bi + rem;
  const int row0 = bi * 128, col0 = bj * 128;

  const int tid = threadIdx.x;
  const int wave = tid >> 6, lane = tid & 63;
  const int wr = (wave >> 1) * 32, wc = (wave & 1) * 64;   // wave's 32x64 sub-tile
  const int fr = lane & 15, q = lane >> 4;

  if (tid < 128) {
    sqi[tid] = sq[row0 + tid]; sqj[tid] = sq[col0 + tid];
    labi_s[tid] = lab[row0 + tid]; labj_s[tid] = lab[col0 + tid];
    hpl[tid] = 0u; nml[tid] = UINF; hpc[tid] = 0u; nmc[tid] = UINF;
  }

  const int srow = lane >> 2;
  const int g16  = (lane & 3) ^ (srow & 3);

  f32x4 acc[2][4];
  #pragma unroll
  for (int a=0;a<2;a++)
    #pragma unroll
    for (int b=0;b<4;b++)
      acc[a][b] = (f32x4){0.f,0.f,0.f,0.f};

  // Prologue: stage tile 0, drain, then pipeline 2 tiles per loop iter.
  STAGE(As0, Bs0, 0);
  __syncthreads();                       // vmcnt(0) drain -> buf0 ready

  for (int p = 0; p < 4; ++p){           // D/64 = 8 tiles, 2 per iteration
    STAGE(As1, Bs1, 2*p + 1);            // issue next-tile loads first
    COMPUTE(As0, Bs0);                   // ds_read + MFMA hide the latency
    __syncthreads();                     // buf1 ready; buf0 free
    if (p < 3) STAGE(As0, Bs0, 2*p + 2);
    COMPUTE(As1, Bs1);
    __syncthreads();
  }

  // Epilogue. C/D layout: col=lane&15, row=(lane>>4)*4+v (shape-determined).
  const int colq = lane & 15, g4 = lane >> 4, rowq = g4 * 4;
  int   labi_r[8]; float sqi_r[8];
  #pragma unroll
  for (int a=0;a<2;a++)
    #pragma unroll
    for (int v=0;v<4;v++){
      const int iloc = wr + a*16 + rowq + v;
      labi_r[a*4+v] = labi_s[iloc];
      sqi_r[a*4+v]  = sqi[iloc];
    }

  float pmax_r[8], nmin_r[8];
  #pragma unroll
  for (int k=0;k<8;k++){ pmax_r[k] = 0.f; nmin_r[k] = FINF; }
  float cpos[4], cmin[4];

  #pragma unroll
  for (int b=0;b<4;b++){
    const int jloc = wc + b*16 + colq;
    const float sj = sqj[jloc];
    const int lj = labj_s[jloc];
    float cp = 0.f, cn = FINF;
    #pragma unroll
    for (int a=0;a<2;a++)
      #pragma unroll
      for (int v=0;v<4;v++){
        const int k = a*4+v;
        const float d2 = fmaf(acc[a][b][v], -2.0f, sqi_r[k] + sj);
        const bool same = (labi_r[k] == lj);         // covers diag (i==j)
        const float sp = same ? d2 : 0.0f;           // positive candidate
        const float sn = same ? FINF : d2;           // negative candidate
        pmax_r[k] = fmaxf(pmax_r[k], sp);
        nmin_r[k] = fminf(nmin_r[k], sn);
        cp = fmaxf(cp, sp);
        cn = fminf(cn, sn);
      }
    cpos[b] = cp; cmin[b] = cn;
  }

  // Row-direction: xor-reduce across the 16 lanes sharing a row -> LDS atomic.
  #pragma unroll
  for (int k=0;k<8;k++){
    float p = pmax_r[k], n = nmin_r[k];
    #pragma unroll
    for (int m=1;m<16;m<<=1){
      p = fmaxf(p, __shfl_xor(p, m, 64));
      n = fminf(n, __shfl_xor(n, m, 64));
    }
    if (colq == 0){
      const int il = wr + (k>>2)*16 + rowq + (k&3);
      atomicMax(&hpl[il], __float_as_uint(p));                 // p >= 0
      atomicMin(&nml[il], __float_as_uint(fmaxf(n, 0.f)));     // clamp: monotone
    }
  }
  // Column-direction (symmetry): xor-reduce across the 4 lane-groups -> LDS atomic.
  #pragma unroll
  for (int b=0;b<4;b++){
    float p = cpos[b], n = cmin[b];
    p = fmaxf(p, __shfl_xor(p, 16, 64)); p = fmaxf(p, __shfl_xor(p, 32, 64));
    n = fminf(n, __shfl_xor(n, 16, 64)); n = fminf(n, __shfl_xor(n, 32, 64));
    if (g4 == 0){
      const int jl = wc + b*16 + colq;
      atomicMax(&hpc[jl], __float_as_uint(p));
      atomicMin(&nmc[jl], __float_as_uint(fmaxf(n, 0.f)));
    }
  }

  __syncthreads();
  // One global flush: threads 0-127 region rows, 128-255 region cols.
  if (tid < 128){
    atomicMax(hp2u + row0 + tid, hpl[tid]);
    atomicMin(nm2u + row0 + tid, nml[tid]);
  } else if (tid < 256){
    const int t2 = tid - 128;
    atomicMax(hp2u + col0 + t2, hpc[t2]);
    atomicMin(nm2u + col0 + t2, nmc[t2]);
  }
}

// Final: loss = mean(sqrt(hp2)) + mean(max(margin - sqrt(nm2), 0)).
// 16 blocks + one atomicAdd per block; out zeroed by prep.
__global__ __launch_bounds__(256) void final_reduce(const unsigned int* __restrict__ hp2u,
    const unsigned int* __restrict__ nm2u, float* __restrict__ out){
  const int i = blockIdx.x * 256 + threadIdx.x;
  const float hp2 = __uint_as_float(hp2u[i]);
  const float nm2 = __uint_as_float(nm2u[i]);
  float s = sqrtf(hp2 + 1e-12f) + fmaxf(MARGIN - sqrtf(nm2 + 1e-12f), 0.f);
  s = wave_sum(s);
  __shared__ float r[4];
  if ((threadIdx.x & 63) == 0) r[threadIdx.x >> 6] = s;
  __syncthreads();
  if (threadIdx.x == 0)
    atomicAdd(out, (r[0] + r[1] + r[2] + r[3]) * (1.0f / (float)N));
}

extern "C" void kernel_launch(void* const* d_in, const int* in_sizes, int n_in,
                              void* d_out, int out_size, void* d_ws, size_t ws_size,
                              hipStream_t stream) {
  (void)in_sizes; (void)n_in; (void)out_size; (void)ws_size;
  const float* X  = (const float*)d_in[0];
  const int* lab  = (const int*)d_in[1];
  float* out      = (float*)d_out;

  char* ws = (char*)d_ws;
  unsigned char* Xq     = (unsigned char*)ws;                  // 2 MB fp8
  float* sq             = (float*)(Xq + (size_t)N * D);        // 16 KB
  unsigned int* hp2u    = (unsigned int*)(sq + N);             // 16 KB
  unsigned int* nm2u    = hp2u + N;                            // 16 KB

  prep_kernel<<<N/8, 256, 0, stream>>>(X, Xq, sq, hp2u, nm2u, out);
  gemm_fused<<<NBLK, 512, 0, stream>>>(Xq, sq, lab, hp2u, nm2u);
  final_reduce<<<16, 256, 0, stream>>>(hp2u, nm2u, out);
}

// Round 11
// 79.919 us; speedup vs baseline: 1.2047x; 1.1117x over previous
//
#include <hip/hip_runtime.h>
#include <hip/hip_bf16.h>
#include <string.h>

#define N 4096
#define D 512
#define NB 32            // N/128 regions; triangle regions = NB*(NB+1)/2 = 528
#define NBLK (NB*(NB+1)/2)
#define MARGIN 0.5f
#define FINF __builtin_huge_valf()
#define UINF 0x7F800000u

typedef __attribute__((ext_vector_type(4))) float f32x4;
typedef long fp8x8;      // 8 packed fp8-e4m3 (i64 MFMA operand)

__device__ inline float wave_sum(float v){
  #pragma unroll
  for (int off=32; off>0; off>>=1) v += __shfl_down(v, off, 64);
  return v;
}

// Pass 0: X (f32) -> fp8 e4m3, row norms, accumulator init. 512 x 256.
__global__ __launch_bounds__(256) void prep_kernel(const float* __restrict__ X,
    unsigned char* __restrict__ Xq, float* __restrict__ sq,
    unsigned int* __restrict__ hp2u, unsigned int* __restrict__ nm2u,
    float* __restrict__ out){
  const int tid = threadIdx.x;
  const int wave = tid >> 6, lane = tid & 63;
  const int l128 = tid & 127;        // 128 threads per row
  const int rsel = tid >> 7;         // which of the 2 rows this pass
  __shared__ float red[4];
  #pragma unroll
  for (int rr = 0; rr < 4; ++rr){    // 8 rows per block
    const int row = blockIdx.x*8 + rr*2 + rsel;
    const float4 v = *(const float4*)(X + (size_t)row*D + l128*4);
    int p0 = __builtin_amdgcn_cvt_pk_fp8_f32(v.x, v.y, 0, false);
    int p1 = __builtin_amdgcn_cvt_pk_fp8_f32(v.z, v.w, 0, false);
    unsigned int packed = (p0 & 0xFFFFu) | ((unsigned int)(p1 & 0xFFFFu) << 16);
    *(unsigned int*)(Xq + (size_t)row*D + l128*4) = packed;
    float ss = v.x*v.x + v.y*v.y + v.z*v.z + v.w*v.w;
    ss = wave_sum(ss);
    if (lane == 0) red[wave] = ss;
    __syncthreads();
    if (tid == 0)   sq[row] = red[0] + red[1];   // rsel==0 row
    if (tid == 128) sq[row] = red[2] + red[3];   // rsel==1 row
    __syncthreads();
  }
  if (tid < 8){
    hp2u[blockIdx.x*8 + tid] = 0u;   // max-accumulator (d^2 domain, >= 0)
    nm2u[blockIdx.x*8 + tid] = UINF; // +inf: min-accumulator
  }
  if (blockIdx.x == 0 && tid == 0) out[0] = 0.0f;
}

// Staging: rows are 64 B = 4 x 16B slots. LDS slot s of row r holds global
// chunk c = s ^ (r&3). Lane l: row = l>>2, slot = l&3 (dest = base+l*16),
// fetches global chunk g = (l&3) ^ ((l>>2)&3). 128 rows: 2 issues/wave.
#define STAGE(Abuf, Bbuf, it) do { \
  const int k0_ = (it)*64; \
  _Pragma("unroll") \
  for (int c_=0;c_<2;c_++){ \
    const int rg_ = wave*32 + c_*16; \
    const unsigned char* ga_ = Xq + (size_t)(row0 + rg_ + srow)*D + k0_ + g16*16; \
    const unsigned char* gb_ = Xq + (size_t)(col0 + rg_ + srow)*D + k0_ + g16*16; \
    __builtin_amdgcn_global_load_lds((const __attribute__((address_space(1))) void*)ga_, \
        (__attribute__((address_space(3))) void*)((Abuf) + rg_*64), 16, 0, 0); \
    __builtin_amdgcn_global_load_lds((const __attribute__((address_space(1))) void*)gb_, \
        (__attribute__((address_space(3))) void*)((Bbuf) + rg_*64), 16, 0, 0); \
  } \
} while(0)

// Fragment reads with wave-quadrant rows: A rows wr+a*16+fr, B rows
// wc+b*16+fr; chunk c_=h*2+(q>>1), half (q&1)*8.
#define COMPUTE(Abuf, Bbuf) do { \
  fp8x8 af_[2][4], bf_[2][4]; \
  _Pragma("unroll") \
  for (int h_=0;h_<2;h_++){ \
    const int c_ = h_*2 + (q>>1); \
    const int hb_ = (q&1)*8; \
    _Pragma("unroll") \
    for (int a_=0;a_<4;a_++){ \
      const int ra_ = wr + a_*16 + fr; \
      af_[h_][a_] = *(const fp8x8*)((Abuf) + ra_*64 + (((c_) ^ (ra_&3))*16) + hb_); \
      const int rb_ = wc + a_*16 + fr; \
      bf_[h_][a_] = *(const fp8x8*)((Bbuf) + rb_*64 + (((c_) ^ (rb_&3))*16) + hb_); \
    } \
  } \
  _Pragma("unroll") \
  for (int h_=0;h_<2;h_++) \
    _Pragma("unroll") \
    for (int a_=0;a_<4;a_++) \
      _Pragma("unroll") \
      for (int b_=0;b_<4;b_++) \
        acc[a_][b_] = __builtin_amdgcn_mfma_f32_16x16x32_fp8_fp8(af_[h_][a_], bf_[h_][b_], acc[a_][b_], 0, 0, 0); \
} while(0)

// Terminal kernel (R8 revert): best-measured configuration, 80.98 us.
// 128x128 dbuf GEMM (528 blocks, 2/CU), wave-quadrant fragment indexing
// (absmax 0.0), 512-WG prep, separate final_reduce. Ten structural
// variants (dbuf/3buf-vmcnt/no-LDS/full-K/occupancy x3/coop/ticket)
// bracket the GEMM at 22-26 us; window is fill(41.6) + gaps-dominated.
__global__ __launch_bounds__(256,2) void gemm_fused(const unsigned char* __restrict__ Xq,
    const float* __restrict__ sq, const int* __restrict__ lab,
    unsigned int* __restrict__ hp2u, unsigned int* __restrict__ nm2u){
  __shared__ __align__(16) unsigned char As0[128*64];   // 8 KB
  __shared__ __align__(16) unsigned char Bs0[128*64];   // 8 KB
  __shared__ __align__(16) unsigned char As1[128*64];   // 8 KB
  __shared__ __align__(16) unsigned char Bs1[128*64];   // 8 KB
  __shared__ float sqi[128];
  __shared__ float sqj[128];
  __shared__ int labi_s[128];
  __shared__ int labj_s[128];
  __shared__ unsigned int hpl[128], nml[128];   // region-row combine
  __shared__ unsigned int hpc[128], nmc[128];   // region-col combine

  // linear block -> region (bi, bj) with bi <= bj
  int rem = blockIdx.x, bi = 0;
  while (rem >= NB - bi){ rem -= NB - bi; bi++; }
  const int bj = bi + rem;
  const int row0 = bi * 128, col0 = bj * 128;

  const int tid = threadIdx.x;
  const int wave = tid >> 6, lane = tid & 63;
  const int wr = (wave >> 1) * 64, wc = (wave & 1) * 64;   // wave's 64x64 quadrant
  const int fr = lane & 15, q = lane >> 4;

  if (tid < 128) {
    sqi[tid] = sq[row0 + tid]; sqj[tid] = sq[col0 + tid];
    labi_s[tid] = lab[row0 + tid]; labj_s[tid] = lab[col0 + tid];
    hpl[tid] = 0u; nml[tid] = UINF; hpc[tid] = 0u; nmc[tid] = UINF;
  }

  const int srow = lane >> 2;
  const int g16  = (lane & 3) ^ (srow & 3);

  f32x4 acc[4][4];
  #pragma unroll
  for (int a=0;a<4;a++)
    #pragma unroll
    for (int b=0;b<4;b++)
      acc[a][b] = (f32x4){0.f,0.f,0.f,0.f};

  // Prologue: stage tile 0, drain, then pipeline 2 tiles per loop iter.
  STAGE(As0, Bs0, 0);
  __syncthreads();                       // vmcnt(0) drain -> buf0 ready

  for (int p = 0; p < 4; ++p){           // D/64 = 8 tiles, 2 per iteration
    STAGE(As1, Bs1, 2*p + 1);            // issue next-tile loads first
    COMPUTE(As0, Bs0);                   // ds_read + MFMA hide the latency
    __syncthreads();                     // buf1 ready; buf0 free
    if (p < 3) STAGE(As0, Bs0, 2*p + 2);
    COMPUTE(As1, Bs1);
    __syncthreads();
  }

  // Epilogue. C/D layout: col=lane&15, row=(lane>>4)*4+v (shape-determined).
  const int colq = lane & 15, g4 = lane >> 4, rowq = g4 * 4;
  int   labi_r[16]; float sqi_r[16];
  #pragma unroll
  for (int a=0;a<4;a++)
    #pragma unroll
    for (int v=0;v<4;v++){
      const int iloc = wr + a*16 + rowq + v;
      labi_r[a*4+v] = labi_s[iloc];
      sqi_r[a*4+v]  = sqi[iloc];
    }

  float pmax_r[16], nmin_r[16];
  #pragma unroll
  for (int k=0;k<16;k++){ pmax_r[k] = 0.f; nmin_r[k] = FINF; }
  float cpos[4], cmin[4];

  #pragma unroll
  for (int b=0;b<4;b++){
    const int jloc = wc + b*16 + colq;
    const float sj = sqj[jloc];
    const int lj = labj_s[jloc];
    float cp = 0.f, cn = FINF;
    #pragma unroll
    for (int a=0;a<4;a++)
      #pragma unroll
      for (int v=0;v<4;v++){
        const int k = a*4+v;
        const float d2 = fmaf(acc[a][b][v], -2.0f, sqi_r[k] + sj);
        const bool same = (labi_r[k] == lj);         // covers diag (i==j)
        const float sp = same ? d2 : 0.0f;           // positive candidate
        const float sn = same ? FINF : d2;           // negative candidate
        pmax_r[k] = fmaxf(pmax_r[k], sp);
        nmin_r[k] = fminf(nmin_r[k], sn);
        cp = fmaxf(cp, sp);
        cn = fminf(cn, sn);
      }
    cpos[b] = cp; cmin[b] = cn;
  }

  // Row-direction: xor-reduce across the 16 lanes sharing a row -> LDS atomic.
  #pragma unroll
  for (int k=0;k<16;k++){
    float p = pmax_r[k], n = nmin_r[k];
    #pragma unroll
    for (int m=1;m<16;m<<=1){
      p = fmaxf(p, __shfl_xor(p, m, 64));
      n = fminf(n, __shfl_xor(n, m, 64));
    }
    if (colq == 0){
      const int il = wr + (k>>2)*16 + rowq + (k&3);
      atomicMax(&hpl[il], __float_as_uint(p));                 // p >= 0
      atomicMin(&nml[il], __float_as_uint(fmaxf(n, 0.f)));     // clamp: monotone
    }
  }
  // Column-direction (symmetry): xor-reduce across the 4 lane-groups -> LDS atomic.
  #pragma unroll
  for (int b=0;b<4;b++){
    float p = cpos[b], n = cmin[b];
    p = fmaxf(p, __shfl_xor(p, 16, 64)); p = fmaxf(p, __shfl_xor(p, 32, 64));
    n = fminf(n, __shfl_xor(n, 16, 64)); n = fminf(n, __shfl_xor(n, 32, 64));
    if (g4 == 0){
      const int jl = wc + b*16 + colq;
      atomicMax(&hpc[jl], __float_as_uint(p));
      atomicMin(&nmc[jl], __float_as_uint(fmaxf(n, 0.f)));
    }
  }

  __syncthreads();
  // One global flush: threads 0-127 do region rows, 128-255 region cols.
  if (tid < 128){
    atomicMax(hp2u + row0 + tid, hpl[tid]);
    atomicMin(nm2u + row0 + tid, nml[tid]);
  } else {
    const int t2 = tid - 128;
    atomicMax(hp2u + col0 + t2, hpc[t2]);
    atomicMin(nm2u + col0 + t2, nmc[t2]);
  }
}

// Final: loss = mean(sqrt(hp2)) + mean(max(margin - sqrt(nm2), 0)).
// 16 blocks + one atomicAdd per block; out zeroed by prep.
__global__ __launch_bounds__(256) void final_reduce(const unsigned int* __restrict__ hp2u,
    const unsigned int* __restrict__ nm2u, float* __restrict__ out){
  const int i = blockIdx.x * 256 + threadIdx.x;
  const float hp2 = __uint_as_float(hp2u[i]);
  const float nm2 = __uint_as_float(nm2u[i]);
  float s = sqrtf(hp2 + 1e-12f) + fmaxf(MARGIN - sqrtf(nm2 + 1e-12f), 0.f);
  s = wave_sum(s);
  __shared__ float r[4];
  if ((threadIdx.x & 63) == 0) r[threadIdx.x >> 6] = s;
  __syncthreads();
  if (threadIdx.x == 0)
    atomicAdd(out, (r[0] + r[1] + r[2] + r[3]) * (1.0f / (float)N));
}

extern "C" void kernel_launch(void* const* d_in, const int* in_sizes, int n_in,
                              void* d_out, int out_size, void* d_ws, size_t ws_size,
                              hipStream_t stream) {
  (void)in_sizes; (void)n_in; (void)out_size; (void)ws_size;
  const float* X  = (const float*)d_in[0];
  const int* lab  = (const int*)d_in[1];
  float* out      = (float*)d_out;

  char* ws = (char*)d_ws;
  unsigned char* Xq     = (unsigned char*)ws;                  // 2 MB fp8
  float* sq             = (float*)(Xq + (size_t)N * D);        // 16 KB
  unsigned int* hp2u    = (unsigned int*)(sq + N);             // 16 KB
  unsigned int* nm2u    = hp2u + N;                            // 16 KB

  prep_kernel<<<N/8, 256, 0, stream>>>(X, Xq, sq, hp2u, nm2u, out);
  gemm_fused<<<NBLK, 256, 0, stream>>>(Xq, sq, lab, hp2u, nm2u);
  final_reduce<<<16, 256, 0, stream>>>(hp2u, nm2u, out);
}